// Round 4
// baseline (3333.692 us; speedup 1.0000x reference)
//
#include <hip/hip_runtime.h>

#define NBUS 131072
#define NGEN 32768
#define NEBB 2097152
#define NEGB 65536
#define NEBG 65536
#define NEBUS (NEBB + NEGB)  // merged bus-dest CSR (bb + gb)

typedef float f32x2 __attribute__((ext_vector_type(2)));
typedef float f32x4 __attribute__((ext_vector_type(4)));
typedef unsigned short u16;
typedef unsigned short u16x4 __attribute__((ext_vector_type(4)));

__device__ inline float bf2f(u16 u) {
  union { unsigned i; float f; } v;
  v.i = (unsigned)u << 16;
  return v.f;
}
__device__ inline f32x4 bf4tof(u16x4 u) {
  f32x4 r;
  r.x = bf2f(u.x); r.y = bf2f(u.y); r.z = bf2f(u.z); r.w = bf2f(u.w);
  return r;
}
__device__ inline u16 f2bf(float f) {  // round-to-nearest-even
  unsigned u = __builtin_bit_cast(unsigned, f);
  unsigned r = u + 0x7FFFu + ((u >> 16) & 1u);
  return (u16)(r >> 16);
}

// ---------------- CSR build ----------------
__global__ void k_hist(const int* __restrict__ dst, int* __restrict__ counts, int nE) {
  int stride = gridDim.x * blockDim.x;
  for (int i = blockIdx.x * blockDim.x + threadIdx.x; i < nE; i += stride)
    atomicAdd(&counts[dst[i]], 1);
}

__global__ void k_scan1(const int* __restrict__ in, int* __restrict__ out,
                        int* __restrict__ bsums, int n) {
  __shared__ int sh[256];
  int t = threadIdx.x;
  int base = blockIdx.x * 1024 + t * 4;
  int v0 = (base + 0 < n) ? in[base + 0] : 0;
  int v1 = (base + 1 < n) ? in[base + 1] : 0;
  int v2 = (base + 2 < n) ? in[base + 2] : 0;
  int v3 = (base + 3 < n) ? in[base + 3] : 0;
  int t0 = v0, t1 = t0 + v1, t2 = t1 + v2, t3 = t2 + v3;
  sh[t] = t3;
  __syncthreads();
  for (int off = 1; off < 256; off <<= 1) {
    int x = (t >= off) ? sh[t - off] : 0;
    __syncthreads();
    sh[t] += x;
    __syncthreads();
  }
  int excl = (t > 0) ? sh[t - 1] : 0;
  if (base + 0 < n) out[base + 0] = excl;
  if (base + 1 < n) out[base + 1] = excl + t0;
  if (base + 2 < n) out[base + 2] = excl + t1;
  if (base + 3 < n) out[base + 3] = excl + t2;
  if (t == 255) bsums[blockIdx.x] = sh[255];
}

__global__ void k_scan2(int* __restrict__ bsums, int nb) {
  __shared__ int sh[256];
  int t = threadIdx.x;
  int v = (t < nb) ? bsums[t] : 0;
  sh[t] = v;
  __syncthreads();
  for (int off = 1; off < 256; off <<= 1) {
    int x = (t >= off) ? sh[t - off] : 0;
    __syncthreads();
    sh[t] += x;
    __syncthreads();
  }
  int excl = (t > 0) ? sh[t - 1] : 0;
  if (t < nb) bsums[t] = excl;
}

__global__ void k_scan3(int* __restrict__ off, int* __restrict__ cur,
                        const int* __restrict__ bsums, int n, int E) {
  int stride = gridDim.x * blockDim.x;
  for (int i = blockIdx.x * blockDim.x + threadIdx.x; i < n; i += stride) {
    int o = off[i] + bsums[i >> 10];
    off[i] = o;
    cur[i] = o;
  }
  if (blockIdx.x == 0 && threadIdx.x == 0) off[n] = E;
}

// srcOff encodes the source-feature section (gen rows live at NBUS+src)
__global__ void k_fill(const int* __restrict__ src, const int* __restrict__ dst,
                       int* __restrict__ cur, int* __restrict__ srt, int nE, int srcOff) {
  int stride = gridDim.x * blockDim.x;
  for (int i = blockIdx.x * blockDim.x + threadIdx.x; i < nE; i += stride) {
    int d = dst[i];
    int p = atomicAdd(&cur[d], 1);
    srt[p] = src[i] + srcOff;
  }
}

// ---------------- readin + fused BN-stats ----------------
__global__ void __launch_bounds__(256) k_readin(const float* __restrict__ x,
                                                const float* __restrict__ W,
                                                const float* __restrict__ b,
                                                float* __restrict__ y, int nRows,
                                                float* __restrict__ stats) {
  __shared__ float Ws[2048];
  __shared__ float bs[64];
  __shared__ float shs[4][64];
  __shared__ float shs2[4][64];
  for (int i = threadIdx.x; i < 2048; i += 256) Ws[i] = W[i];
  if (threadIdx.x < 64) bs[threadIdx.x] = b[threadIdx.x];
  __syncthreads();
  int lane = threadIdx.x & 63;
  int wib = threadIdx.x >> 6;
  int w = (blockIdx.x * blockDim.x + threadIdx.x) >> 6;
  int nw = (gridDim.x * blockDim.x) >> 6;
  float ls = 0.f, ls2 = 0.f;
  for (int r = w; r < nRows; r += nw) {
    float v = x[(size_t)r * 32 + (lane & 31)];
    float acc = bs[lane];
#pragma unroll
    for (int i = 0; i < 32; i++) {
      float xi = __shfl(v, i, 64);
      acc = fmaf(xi, Ws[i * 64 + lane], acc);
    }
    y[(size_t)r * 64 + lane] = acc;
    ls += acc;
    ls2 = fmaf(acc, acc, ls2);
  }
  shs[wib][lane] = ls;
  shs2[wib][lane] = ls2;
  __syncthreads();
  if (threadIdx.x < 64) {
    int c = threadIdx.x;
    atomicAdd(&stats[c], shs[0][c] + shs[1][c] + shs[2][c] + shs[3][c]);
  } else if (threadIdx.x < 128) {
    int c = threadIdx.x & 63;
    atomicAdd(&stats[64 + c], shs2[0][c] + shs2[1][c] + shs2[2][c] + shs2[3][c]);
  }
}

// ---------------- fused BN-finalize + normalize + lrelu + tap0 (c out in bf16) ----------------
__global__ void __launch_bounds__(256) k_norm_tap0(float* __restrict__ x,
                                                   u16* __restrict__ c0,
                                                   const float* __restrict__ stats, float invN,
                                                   const float* __restrict__ gamma,
                                                   const float* __restrict__ beta,
                                                   const float* __restrict__ W,
                                                   const float* __restrict__ b, int nRows) {
  __shared__ float Ws[4096];
  for (int i = threadIdx.x; i < 4096; i += 256) Ws[i] = W[i];
  __syncthreads();
  int lane = threadIdx.x & 63;
  float m = stats[lane] * invN;
  float m2 = stats[64 + lane] * invN;
  float rs = rsqrtf(m2 - m * m + 1e-5f);
  float scale = gamma[lane] * rs;
  float shift = beta[lane] - m * scale;
  float bv = b[lane];
  int w = (blockIdx.x * blockDim.x + threadIdx.x) >> 6;
  int nw = (gridDim.x * blockDim.x) >> 6;
  for (int r = w; r < nRows; r += nw) {
    size_t idx = (size_t)r * 64 + lane;
    float xv = x[idx];
    float y = fmaf(xv, scale, shift);
    y = (y >= 0.f) ? y : 0.01f * y;
    c0[idx] = f2bf(y);  // gather source for next shift (bf16)
    float acc = bv;
#pragma unroll
    for (int i = 0; i < 64; i++) {
      float yi = __shfl(y, i, 64);
      acc = fmaf(yi, Ws[i * 64 + lane], acc);
    }
    __builtin_nontemporal_store(xv + acc, &x[idx]);
  }
}

// ---------------- fused shift (merged CSR pull, bf16 src) + tap GEMM + optional BN-stats ----
// 4 dest rows per wave (16 lanes/row, 4 channels/lane). Up to 32 outstanding
// gather loads per wave; x residual prefetched at iteration top.
__global__ void __launch_bounds__(256) k_pull_tap(
    const int* __restrict__ off, const int* __restrict__ srt,
    const u16* __restrict__ call,
    float* __restrict__ x, u16* __restrict__ nout,
    const float* __restrict__ W, const float* __restrict__ b,
    int nRows, float* __restrict__ stats) {
  __shared__ float Ws[4096];
  __shared__ f32x4 shS[256];
  __shared__ f32x4 shS2[256];
  for (int i = threadIdx.x; i < 4096; i += 256) Ws[i] = W[i];
  __syncthreads();
  const int lane = threadIdx.x & 63;
  const int q = lane >> 4;    // which row of the quad this lane serves
  const int sub = lane & 15;  // channel-quad index within the row
  const int c0 = sub * 4;
  const int q16 = q * 16;
  const f32x4 bv = *(const f32x4*)&b[c0];
  f32x4 ls = {0.f, 0.f, 0.f, 0.f}, ls2 = {0.f, 0.f, 0.f, 0.f};
  int w = (blockIdx.x * blockDim.x + threadIdx.x) >> 6;
  int nw = (gridDim.x * blockDim.x) >> 6;
  int nQ = nRows >> 2;
  int begN = 0, endN = 0, slN = 0;
  if (w < nQ) {
    int rN = w * 4 + q;
    begN = off[rN];
    endN = off[rN + 1];
    slN = (begN + sub < endN) ? srt[begN + sub] : 0;
  }
  for (int qd = w; qd < nQ; qd += nw) {
    int r = qd * 4 + q;
    int beg = begN, end = endN;
    int sl_cur = slN;
    int qn = qd + nw;
    if (qn < nQ) {  // prefetch next quad's offsets
      int rn = qn * 4 + q;
      begN = off[rn];
      endN = off[rn + 1];
    }
    size_t idx = (size_t)r * 64 + c0;
    f32x4 xv = *(const f32x4*)&x[idx];  // early: hides under gather
    f32x4 a0 = {0, 0, 0, 0}, a1 = {0, 0, 0, 0}, a2 = {0, 0, 0, 0}, a3 = {0, 0, 0, 0};
    for (int base = beg; base < end; base += 16) {
      int nn = end - base;
      if (nn > 16) nn = 16;
      int sl_nx = 0;
      if (base + 16 < end)
        sl_nx = (base + 16 + sub < end) ? srt[base + 16 + sub] : 0;
      int j = 0;
      for (; j + 8 <= nn; j += 8) {
        int s0 = __shfl(sl_cur, q16 + j + 0, 64);
        int s1 = __shfl(sl_cur, q16 + j + 1, 64);
        int s2 = __shfl(sl_cur, q16 + j + 2, 64);
        int s3 = __shfl(sl_cur, q16 + j + 3, 64);
        int s4 = __shfl(sl_cur, q16 + j + 4, 64);
        int s5 = __shfl(sl_cur, q16 + j + 5, 64);
        int s6 = __shfl(sl_cur, q16 + j + 6, 64);
        int s7 = __shfl(sl_cur, q16 + j + 7, 64);
        u16x4 u0 = *(const u16x4*)&call[(size_t)s0 * 64 + c0];
        u16x4 u1 = *(const u16x4*)&call[(size_t)s1 * 64 + c0];
        u16x4 u2 = *(const u16x4*)&call[(size_t)s2 * 64 + c0];
        u16x4 u3 = *(const u16x4*)&call[(size_t)s3 * 64 + c0];
        u16x4 u4 = *(const u16x4*)&call[(size_t)s4 * 64 + c0];
        u16x4 u5 = *(const u16x4*)&call[(size_t)s5 * 64 + c0];
        u16x4 u6 = *(const u16x4*)&call[(size_t)s6 * 64 + c0];
        u16x4 u7 = *(const u16x4*)&call[(size_t)s7 * 64 + c0];
        a0 += bf4tof(u0); a1 += bf4tof(u1); a2 += bf4tof(u2); a3 += bf4tof(u3);
        a0 += bf4tof(u4); a1 += bf4tof(u5); a2 += bf4tof(u6); a3 += bf4tof(u7);
      }
      for (; j + 4 <= nn; j += 4) {
        int s0 = __shfl(sl_cur, q16 + j + 0, 64);
        int s1 = __shfl(sl_cur, q16 + j + 1, 64);
        int s2 = __shfl(sl_cur, q16 + j + 2, 64);
        int s3 = __shfl(sl_cur, q16 + j + 3, 64);
        u16x4 u0 = *(const u16x4*)&call[(size_t)s0 * 64 + c0];
        u16x4 u1 = *(const u16x4*)&call[(size_t)s1 * 64 + c0];
        u16x4 u2 = *(const u16x4*)&call[(size_t)s2 * 64 + c0];
        u16x4 u3 = *(const u16x4*)&call[(size_t)s3 * 64 + c0];
        a0 += bf4tof(u0); a1 += bf4tof(u1); a2 += bf4tof(u2); a3 += bf4tof(u3);
      }
      for (; j < nn; j++) {
        int s = __shfl(sl_cur, q16 + j, 64);
        a0 += bf4tof(*(const u16x4*)&call[(size_t)s * 64 + c0]);
      }
      sl_cur = sl_nx;
    }
    if (qn < nQ)  // prefetch next quad's first srt chunk (hides under GEMM)
      slN = (begN + sub < endN) ? srt[begN + sub] : 0;
    f32x4 acc = (a0 + a1) + (a2 + a3);
    u16x4 nb4;
    nb4.x = f2bf(acc.x); nb4.y = f2bf(acc.y); nb4.z = f2bf(acc.z); nb4.w = f2bf(acc.w);
    *(u16x4*)&nout[idx] = nb4;  // gather source for next shift (bf16)
    f32x4 z = bv;
#pragma unroll
    for (int t = 0; t < 16; ++t) {
      int sl_ = q16 + t;
      float ax = __shfl(acc.x, sl_, 64);
      float ay = __shfl(acc.y, sl_, 64);
      float az = __shfl(acc.z, sl_, 64);
      float aw = __shfl(acc.w, sl_, 64);
      f32x4 w0 = *(const f32x4*)&Ws[(4 * t + 0) * 64 + c0];
      f32x4 w1 = *(const f32x4*)&Ws[(4 * t + 1) * 64 + c0];
      f32x4 w2 = *(const f32x4*)&Ws[(4 * t + 2) * 64 + c0];
      f32x4 w3 = *(const f32x4*)&Ws[(4 * t + 3) * 64 + c0];
      z += ax * w0;
      z += ay * w1;
      z += az * w2;
      z += aw * w3;
    }
    f32x4 xo = xv + z;
    __builtin_nontemporal_store(xo, (f32x4*)&x[idx]);
    ls += xo;
    ls2 += xo * xo;
  }
  if (stats) {
    shS[threadIdx.x] = ls;
    shS2[threadIdx.x] = ls2;
    __syncthreads();
    if (threadIdx.x < 16) {
      f32x4 s = shS[threadIdx.x], s2 = shS2[threadIdx.x];
      for (int t = threadIdx.x + 16; t < 256; t += 16) {
        s += shS[t];
        s2 += shS2[t];
      }
      int c = threadIdx.x * 4;
      atomicAdd(&stats[c + 0], s.x);
      atomicAdd(&stats[c + 1], s.y);
      atomicAdd(&stats[c + 2], s.z);
      atomicAdd(&stats[c + 3], s.w);
      atomicAdd(&stats[64 + c + 0], s2.x);
      atomicAdd(&stats[64 + c + 1], s2.y);
      atomicAdd(&stats[64 + c + 2], s2.z);
      atomicAdd(&stats[64 + c + 3], s2.w);
    }
  }
}

// ---------------- readout ----------------
__global__ void __launch_bounds__(256) k_readout(const float* __restrict__ x,
                                                 const float* __restrict__ W,
                                                 const float* __restrict__ b,
                                                 float* __restrict__ out, int nRows) {
  __shared__ float Ws[2048];
  __shared__ float bs[32];
  for (int i = threadIdx.x; i < 2048; i += 256) Ws[i] = W[i];
  if (threadIdx.x < 32) bs[threadIdx.x] = b[threadIdx.x];
  __syncthreads();
  int lane = threadIdx.x & 63;
  int ch = lane & 31;
  int w = (blockIdx.x * blockDim.x + threadIdx.x) >> 6;
  int nw = (gridDim.x * blockDim.x) >> 6;
  for (int r = w; r < nRows; r += nw) {
    float v = x[(size_t)r * 64 + lane];
    float acc = bs[ch];
#pragma unroll
    for (int i = 0; i < 64; i++) {
      float xi = __shfl(v, i, 64);
      acc = fmaf(xi, Ws[i * 32 + ch], acc);
    }
    if (lane < 32) out[(size_t)r * 32 + ch] = acc;
  }
}

extern "C" void kernel_launch(void* const* d_in, const int* in_sizes, int n_in,
                              void* d_out, int out_size, void* d_ws, size_t ws_size,
                              hipStream_t stream) {
  const float* x_bus = (const float*)d_in[0];
  const float* x_gen = (const float*)d_in[1];
  const float* riWb = (const float*)d_in[2];
  const float* ribb = (const float*)d_in[3];
  const float* riWg = (const float*)d_in[4];
  const float* ribg = (const float*)d_in[5];
  const float* bng_b = (const float*)d_in[6];
  const float* bnb_b = (const float*)d_in[7];
  const float* bng_g = (const float*)d_in[8];
  const float* bnb_g = (const float*)d_in[9];
  const float* tWb = (const float*)d_in[10];
  const float* tbb = (const float*)d_in[11];
  const float* tWg = (const float*)d_in[12];
  const float* tbg = (const float*)d_in[13];
  const float* roWb = (const float*)d_in[14];
  const float* robb = (const float*)d_in[15];
  const float* roWg = (const float*)d_in[16];
  const float* robg = (const float*)d_in[17];
  const int* ebb = (const int*)d_in[18];
  const int* gb_src = (const int*)d_in[19];
  const int* gb_dst = (const int*)d_in[20];
  const int* bg_src = (const int*)d_in[21];
  const int* bg_dst = (const int*)d_in[22];
  const int* bb_src = ebb;
  const int* bb_dst = ebb + NEBB;

  // ---- workspace layout (256B aligned segments) ----
  char* p = (char*)d_ws;
  auto take = [&](size_t bytes) -> void* {
    void* r = (void*)p;
    p += (bytes + 255) & ~(size_t)255;
    return r;
  };
  float* xb = (float*)take((size_t)NBUS * 64 * 4);
  float* xg = (float*)take((size_t)NGEN * 64 * 4);
  // combined bf16 feature buffers: bus rows [0,NBUS), gen rows [NBUS, NBUS+NGEN)
  u16* buf0 = (u16*)take((size_t)(NBUS + NGEN) * 64 * 2);
  u16* buf1 = (u16*)take((size_t)(NBUS + NGEN) * 64 * 2);
  int* bus_off = (int*)take((size_t)(NBUS + 1) * 4);
  int* bus_cur = (int*)take((size_t)NBUS * 4);
  int* bus_srt = (int*)take((size_t)NEBUS * 4);
  int* bg_off = (int*)take((size_t)(NGEN + 1) * 4);
  int* bg_cur = (int*)take((size_t)NGEN * 4);
  int* bg_srt = (int*)take((size_t)NEBG * 4);
  int* bsums = (int*)take(256 * 4);
  float* stats0 = (float*)take(256 * 4);  // [bus s, bus s2, gen s, gen s2]
  float* stats1 = (float*)take(256 * 4);
  if ((size_t)(p - (char*)d_ws) > ws_size) return;  // ws too small -> visible validation failure

  // ---- CSR build (merged bus CSR: bb edges + gb edges with src+NBUS) ----
  hipMemsetAsync(bus_cur, 0, (size_t)NBUS * 4, stream);
  hipMemsetAsync(bg_cur, 0, (size_t)NGEN * 4, stream);
  hipMemsetAsync(stats0, 0, 512 * 4, stream);  // stats0 + stats1 (contiguous)

  k_hist<<<2048, 256, 0, stream>>>(bb_dst, bus_cur, NEBB);
  k_hist<<<256, 256, 0, stream>>>(gb_dst, bus_cur, NEGB);
  k_hist<<<256, 256, 0, stream>>>(bg_dst, bg_cur, NEBG);

  k_scan1<<<128, 256, 0, stream>>>(bus_cur, bus_off, bsums, NBUS);
  k_scan2<<<1, 256, 0, stream>>>(bsums, 128);
  k_scan3<<<512, 256, 0, stream>>>(bus_off, bus_cur, bsums, NBUS, NEBUS);

  k_scan1<<<32, 256, 0, stream>>>(bg_cur, bg_off, bsums, NGEN);
  k_scan2<<<1, 256, 0, stream>>>(bsums, 32);
  k_scan3<<<128, 256, 0, stream>>>(bg_off, bg_cur, bsums, NGEN, NEBG);

  k_fill<<<2048, 256, 0, stream>>>(bb_src, bb_dst, bus_cur, bus_srt, NEBB, 0);
  k_fill<<<256, 256, 0, stream>>>(gb_src, gb_dst, bus_cur, bus_srt, NEGB, NBUS);
  k_fill<<<256, 256, 0, stream>>>(bg_src, bg_dst, bg_cur, bg_srt, NEBG, 0);

  // ---- readin (+ layer-0 BN stats) ----
  k_readin<<<4096, 256, 0, stream>>>(x_bus, riWb, ribb, xb, NBUS, stats0);
  k_readin<<<1024, 256, 0, stream>>>(x_gen, riWg, ribg, xg, NGEN, stats0 + 128);

  // ---- residual blocks ----
  u16* cur = buf0;
  u16* nxt = buf1;
  for (int l = 0; l < 2; l++) {
    float* statsL = (l == 0) ? stats0 : stats1;
    k_norm_tap0<<<4096, 256, 0, stream>>>(xb, cur, statsL, 1.0f / NBUS,
                                          bng_b + l * 64, bnb_b + l * 64,
                                          tWb + (size_t)(l * 5) * 4096,
                                          tbb + (size_t)(l * 5) * 64, NBUS);
    k_norm_tap0<<<1024, 256, 0, stream>>>(xg, cur + (size_t)NBUS * 64, statsL + 128, 1.0f / NGEN,
                                          bng_g + l * 64, bnb_g + l * 64,
                                          tWg + (size_t)(l * 5) * 4096,
                                          tbg + (size_t)(l * 5) * 64, NGEN);
    for (int k = 1; k < 5; k++) {
      float* so = (l == 0 && k == 4) ? stats1 : (float*)nullptr;
      k_pull_tap<<<4096, 256, 0, stream>>>(bus_off, bus_srt, cur, xb, nxt,
                                           tWb + (size_t)(l * 5 + k) * 4096,
                                           tbb + (size_t)(l * 5 + k) * 64, NBUS, so);
      k_pull_tap<<<1024, 256, 0, stream>>>(bg_off, bg_srt, cur, xg, nxt + (size_t)NBUS * 64,
                                           tWg + (size_t)(l * 5 + k) * 4096,
                                           tbg + (size_t)(l * 5 + k) * 64, NGEN,
                                           so ? so + 128 : (float*)nullptr);
      u16* t = cur; cur = nxt; nxt = t;
    }
  }

  // ---- readout ----
  k_readout<<<4096, 256, 0, stream>>>(xb, roWb, robb, (float*)d_out, NBUS);
  k_readout<<<1024, 256, 0, stream>>>(xg, roWg, robg, (float*)d_out + (size_t)NBUS * 32, NGEN);
}

// Round 5
// 1983.449 us; speedup vs baseline: 1.6808x; 1.6808x over previous
//
#include <hip/hip_runtime.h>

#define NBUS 131072
#define NGEN 32768
#define NALL (NBUS + NGEN)
#define NEBB 2097152
#define NEGB 65536
#define NEBG 65536
#define NEBUS (NEBB + NEGB)  // merged bus-dest CSR (bb + gb)

typedef float f32x2 __attribute__((ext_vector_type(2)));
typedef unsigned short u16;

__device__ inline f32x2 bf2x2(unsigned v) {  // unpack 2 bf16 (packed u32) -> 2 f32
  f32x2 r;
  r.x = __builtin_bit_cast(float, v << 16);
  r.y = __builtin_bit_cast(float, v & 0xFFFF0000u);
  return r;
}
__device__ inline u16 f2bf(float f) {  // round-to-nearest-even
  unsigned u = __builtin_bit_cast(unsigned, f);
  unsigned r = u + 0x7FFFu + ((u >> 16) & 1u);
  return (u16)(r >> 16);
}
__device__ inline unsigned pack2bf(float a, float b) {
  return (unsigned)f2bf(a) | ((unsigned)f2bf(b) << 16);
}

// ---------------- CSR build ----------------
__global__ void k_hist(const int* __restrict__ dst, int* __restrict__ counts, int nE) {
  int stride = gridDim.x * blockDim.x;
  for (int i = blockIdx.x * blockDim.x + threadIdx.x; i < nE; i += stride)
    atomicAdd(&counts[dst[i]], 1);
}

__global__ void k_scan1(const int* __restrict__ in, int* __restrict__ out,
                        int* __restrict__ bsums, int n) {
  __shared__ int sh[256];
  int t = threadIdx.x;
  int base = blockIdx.x * 1024 + t * 4;
  int v0 = (base + 0 < n) ? in[base + 0] : 0;
  int v1 = (base + 1 < n) ? in[base + 1] : 0;
  int v2 = (base + 2 < n) ? in[base + 2] : 0;
  int v3 = (base + 3 < n) ? in[base + 3] : 0;
  int t0 = v0, t1 = t0 + v1, t2 = t1 + v2, t3 = t2 + v3;
  sh[t] = t3;
  __syncthreads();
  for (int off = 1; off < 256; off <<= 1) {
    int x = (t >= off) ? sh[t - off] : 0;
    __syncthreads();
    sh[t] += x;
    __syncthreads();
  }
  int excl = (t > 0) ? sh[t - 1] : 0;
  if (base + 0 < n) out[base + 0] = excl;
  if (base + 1 < n) out[base + 1] = excl + t0;
  if (base + 2 < n) out[base + 2] = excl + t1;
  if (base + 3 < n) out[base + 3] = excl + t2;
  if (t == 255) bsums[blockIdx.x] = sh[255];
}

__global__ void k_scan2(int* __restrict__ bsums, int nb) {
  __shared__ int sh[256];
  int t = threadIdx.x;
  int v = (t < nb) ? bsums[t] : 0;
  sh[t] = v;
  __syncthreads();
  for (int off = 1; off < 256; off <<= 1) {
    int x = (t >= off) ? sh[t - off] : 0;
    __syncthreads();
    sh[t] += x;
    __syncthreads();
  }
  int excl = (t > 0) ? sh[t - 1] : 0;
  if (t < nb) bsums[t] = excl;
}

__global__ void k_scan3(int* __restrict__ off, int* __restrict__ cur,
                        const int* __restrict__ bsums, int n, int E) {
  int stride = gridDim.x * blockDim.x;
  for (int i = blockIdx.x * blockDim.x + threadIdx.x; i < n; i += stride) {
    int o = off[i] + bsums[i >> 10];
    off[i] = o;
    cur[i] = o;
  }
  if (blockIdx.x == 0 && threadIdx.x == 0) off[n] = E;
}

// srcOff encodes the source-feature section (gen rows live at NBUS+src)
__global__ void k_fill(const int* __restrict__ src, const int* __restrict__ dst,
                       int* __restrict__ cur, int* __restrict__ srt, int nE, int srcOff) {
  int stride = gridDim.x * blockDim.x;
  for (int i = blockIdx.x * blockDim.x + threadIdx.x; i < nE; i += stride) {
    int d = dst[i];
    int p = atomicAdd(&cur[d], 1);
    srt[p] = src[i] + srcOff;
  }
}

// ---------------- merged readin (bus+gen rows) + fused BN-stats ----------------
__global__ void __launch_bounds__(256) k_readin(const float* __restrict__ xbus,
                                                const float* __restrict__ xgen,
                                                const float* __restrict__ Wb,
                                                const float* __restrict__ bb_,
                                                const float* __restrict__ Wg,
                                                const float* __restrict__ bg_,
                                                float* __restrict__ y,
                                                float* __restrict__ stats) {
  __shared__ float WsB[2048];
  __shared__ float WsG[2048];
  __shared__ float shs[4][64];
  __shared__ float shs2[4][64];
  for (int i = threadIdx.x; i < 2048; i += 256) {
    WsB[i] = Wb[i];
    WsG[i] = Wg[i];
  }
  __syncthreads();
  int lane = threadIdx.x & 63;
  int wib = threadIdx.x >> 6;
  float bvB = bb_[lane], bvG = bg_[lane];
  int w = (blockIdx.x * blockDim.x + threadIdx.x) >> 6;
  int nw = (gridDim.x * blockDim.x) >> 6;
  float lsB = 0.f, ls2B = 0.f, lsG = 0.f, ls2G = 0.f;
  for (int g = w; g < NALL; g += nw) {
    bool isBus = g < NBUS;
    const float* xin = isBus ? xbus : xgen;
    int rl = isBus ? g : g - NBUS;
    const float* Ws = isBus ? WsB : WsG;
    float v = xin[(size_t)rl * 32 + (lane & 31)];
    float acc = isBus ? bvB : bvG;
#pragma unroll
    for (int i = 0; i < 32; i++) {
      float xi = __shfl(v, i, 64);
      acc = fmaf(xi, Ws[i * 64 + lane], acc);
    }
    y[(size_t)g * 64 + lane] = acc;
    if (isBus) {
      lsB += acc;
      ls2B = fmaf(acc, acc, ls2B);
    } else {
      lsG += acc;
      ls2G = fmaf(acc, acc, ls2G);
    }
  }
  shs[wib][lane] = lsB;
  shs2[wib][lane] = ls2B;
  __syncthreads();
  if (threadIdx.x < 64) {
    int c = threadIdx.x;
    atomicAdd(&stats[c], shs[0][c] + shs[1][c] + shs[2][c] + shs[3][c]);
  } else if (threadIdx.x < 128) {
    int c = threadIdx.x & 63;
    atomicAdd(&stats[64 + c], shs2[0][c] + shs2[1][c] + shs2[2][c] + shs2[3][c]);
  }
  __syncthreads();
  shs[wib][lane] = lsG;
  shs2[wib][lane] = ls2G;
  __syncthreads();
  if (threadIdx.x < 64) {
    int c = threadIdx.x;
    atomicAdd(&stats[128 + c], shs[0][c] + shs[1][c] + shs[2][c] + shs[3][c]);
  } else if (threadIdx.x < 128) {
    int c = threadIdx.x & 63;
    atomicAdd(&stats[192 + c], shs2[0][c] + shs2[1][c] + shs2[2][c] + shs2[3][c]);
  }
}

// ---------------- merged BN-finalize + normalize + lrelu + tap0 (c out bf16) ----------------
__global__ void __launch_bounds__(256) k_norm_tap0(float* __restrict__ x,
                                                   u16* __restrict__ c0,
                                                   const float* __restrict__ stats,
                                                   const float* __restrict__ gammaB,
                                                   const float* __restrict__ betaB,
                                                   const float* __restrict__ gammaG,
                                                   const float* __restrict__ betaG,
                                                   const float* __restrict__ Wb,
                                                   const float* __restrict__ bb_,
                                                   const float* __restrict__ Wg,
                                                   const float* __restrict__ bg_) {
  __shared__ float WsB[4096];
  __shared__ float WsG[4096];
  for (int i = threadIdx.x; i < 4096; i += 256) {
    WsB[i] = Wb[i];
    WsG[i] = Wg[i];
  }
  __syncthreads();
  int lane = threadIdx.x & 63;
  float mB = stats[lane] * (1.0f / NBUS);
  float m2B = stats[64 + lane] * (1.0f / NBUS);
  float rsB = rsqrtf(m2B - mB * mB + 1e-5f);
  float scaleB = gammaB[lane] * rsB;
  float shiftB = betaB[lane] - mB * scaleB;
  float mG = stats[128 + lane] * (1.0f / NGEN);
  float m2G = stats[192 + lane] * (1.0f / NGEN);
  float rsG = rsqrtf(m2G - mG * mG + 1e-5f);
  float scaleG = gammaG[lane] * rsG;
  float shiftG = betaG[lane] - mG * scaleG;
  float bvB = bb_[lane], bvG = bg_[lane];
  int w = (blockIdx.x * blockDim.x + threadIdx.x) >> 6;
  int nw = (gridDim.x * blockDim.x) >> 6;
  for (int g = w; g < NALL; g += nw) {
    bool isBus = g < NBUS;
    float scale = isBus ? scaleB : scaleG;
    float shift = isBus ? shiftB : shiftG;
    const float* Ws = isBus ? WsB : WsG;
    size_t idx = (size_t)g * 64 + lane;
    float xv = x[idx];
    float y = fmaf(xv, scale, shift);
    y = (y >= 0.f) ? y : 0.01f * y;
    c0[idx] = f2bf(y);  // gather source for next shift (bf16)
    float acc = isBus ? bvB : bvG;
#pragma unroll
    for (int i = 0; i < 64; i++) {
      float yi = __shfl(y, i, 64);
      acc = fmaf(yi, Ws[i * 64 + lane], acc);
    }
    x[idx] = xv + acc;
  }
}

// ---------------- merged fused shift (CSR pull, bf16 src) + tap GEMM + optional BN-stats ----
// 2 rows/wave (32 lanes/row, 2 channels/lane), 8 gather loads in flight.
__global__ void __launch_bounds__(256) k_pull_tap(
    const int* __restrict__ busOff, const int* __restrict__ busSrt,
    const int* __restrict__ bgOff, const int* __restrict__ bgSrt,
    const u16* __restrict__ call,
    float* __restrict__ x, u16* __restrict__ nout,
    const float* __restrict__ Wb, const float* __restrict__ bb_,
    const float* __restrict__ Wg, const float* __restrict__ bg_,
    float* __restrict__ stats) {
  __shared__ float WsB[4096];
  __shared__ float WsG[4096];
  __shared__ f32x2 shS[256];
  __shared__ f32x2 shS2[256];
  for (int i = threadIdx.x; i < 4096; i += 256) {
    WsB[i] = Wb[i];
    WsG[i] = Wg[i];
  }
  __syncthreads();
  const int lane = threadIdx.x & 63;
  const int half = lane >> 5;
  const int sub = lane & 31;
  const int c0 = sub * 2;
  const int h32 = half * 32;
  const f32x2 bvB = *(const f32x2*)&bb_[c0];
  const f32x2 bvG = *(const f32x2*)&bg_[c0];
  f32x2 lsB = {0.f, 0.f}, ls2B = {0.f, 0.f}, lsG = {0.f, 0.f}, ls2G = {0.f, 0.f};
  int w = (blockIdx.x * blockDim.x + threadIdx.x) >> 6;
  int nw = (gridDim.x * blockDim.x) >> 6;
  const int PB = NBUS / 2, PT = NALL / 2;
  for (int pr = w; pr < PT; pr += nw) {
    bool isBus = pr < PB;
    int g = pr * 2 + half;  // global row (x / call / nout index)
    const int* off = isBus ? busOff : bgOff;
    const int* srt = isBus ? busSrt : bgSrt;
    int rr = isBus ? g : g - NBUS;
    int beg = off[rr], end = off[rr + 1];
    f32x2 a0 = {0.f, 0.f}, a1 = {0.f, 0.f}, a2 = {0.f, 0.f}, a3 = {0.f, 0.f};
    for (int base = beg; base < end; base += 32) {
      int nn = end - base;
      if (nn > 32) nn = 32;
      int sl = (base + sub < end) ? srt[base + sub] : 0;
      int j = 0;
      for (; j + 8 <= nn; j += 8) {
        int s0 = __shfl(sl, h32 + j + 0, 64);
        int s1 = __shfl(sl, h32 + j + 1, 64);
        int s2 = __shfl(sl, h32 + j + 2, 64);
        int s3 = __shfl(sl, h32 + j + 3, 64);
        int s4 = __shfl(sl, h32 + j + 4, 64);
        int s5 = __shfl(sl, h32 + j + 5, 64);
        int s6 = __shfl(sl, h32 + j + 6, 64);
        int s7 = __shfl(sl, h32 + j + 7, 64);
        unsigned v0 = *(const unsigned*)&call[(size_t)s0 * 64 + c0];
        unsigned v1 = *(const unsigned*)&call[(size_t)s1 * 64 + c0];
        unsigned v2 = *(const unsigned*)&call[(size_t)s2 * 64 + c0];
        unsigned v3 = *(const unsigned*)&call[(size_t)s3 * 64 + c0];
        unsigned v4 = *(const unsigned*)&call[(size_t)s4 * 64 + c0];
        unsigned v5 = *(const unsigned*)&call[(size_t)s5 * 64 + c0];
        unsigned v6 = *(const unsigned*)&call[(size_t)s6 * 64 + c0];
        unsigned v7 = *(const unsigned*)&call[(size_t)s7 * 64 + c0];
        a0 += bf2x2(v0); a1 += bf2x2(v1); a2 += bf2x2(v2); a3 += bf2x2(v3);
        a0 += bf2x2(v4); a1 += bf2x2(v5); a2 += bf2x2(v6); a3 += bf2x2(v7);
      }
      for (; j + 4 <= nn; j += 4) {
        int s0 = __shfl(sl, h32 + j + 0, 64);
        int s1 = __shfl(sl, h32 + j + 1, 64);
        int s2 = __shfl(sl, h32 + j + 2, 64);
        int s3 = __shfl(sl, h32 + j + 3, 64);
        unsigned v0 = *(const unsigned*)&call[(size_t)s0 * 64 + c0];
        unsigned v1 = *(const unsigned*)&call[(size_t)s1 * 64 + c0];
        unsigned v2 = *(const unsigned*)&call[(size_t)s2 * 64 + c0];
        unsigned v3 = *(const unsigned*)&call[(size_t)s3 * 64 + c0];
        a0 += bf2x2(v0); a1 += bf2x2(v1); a2 += bf2x2(v2); a3 += bf2x2(v3);
      }
      for (; j < nn; j++) {
        int s = __shfl(sl, h32 + j, 64);
        a0 += bf2x2(*(const unsigned*)&call[(size_t)s * 64 + c0]);
      }
    }
    f32x2 acc = (a0 + a1) + (a2 + a3);
    size_t idx = (size_t)g * 64 + c0;
    *(unsigned*)&nout[idx] = pack2bf(acc.x, acc.y);  // gather source for next shift
    const float* Ws = isBus ? WsB : WsG;
    f32x2 bv = isBus ? bvB : bvG;
    float zx = bv.x, zy = bv.y;
#pragma unroll
    for (int t = 0; t < 32; ++t) {
      float nx = __shfl(acc.x, h32 + t, 64);
      float ny = __shfl(acc.y, h32 + t, 64);
      f32x2 w0 = *(const f32x2*)&Ws[(2 * t) * 64 + c0];
      f32x2 w1 = *(const f32x2*)&Ws[(2 * t + 1) * 64 + c0];
      zx = fmaf(nx, w0.x, zx);
      zy = fmaf(nx, w0.y, zy);
      zx = fmaf(ny, w1.x, zx);
      zy = fmaf(ny, w1.y, zy);
    }
    f32x2 xv = *(const f32x2*)&x[idx];
    f32x2 xo = {xv.x + zx, xv.y + zy};
    *(f32x2*)&x[idx] = xo;
    if (isBus) {
      lsB += xo;
      ls2B.x = fmaf(xo.x, xo.x, ls2B.x);
      ls2B.y = fmaf(xo.y, xo.y, ls2B.y);
    } else {
      lsG += xo;
      ls2G.x = fmaf(xo.x, xo.x, ls2G.x);
      ls2G.y = fmaf(xo.y, xo.y, ls2G.y);
    }
  }
  if (stats) {
    shS[threadIdx.x] = lsB;
    shS2[threadIdx.x] = ls2B;
    __syncthreads();
    if (threadIdx.x < 32) {
      f32x2 s = shS[threadIdx.x], s2 = shS2[threadIdx.x];
      for (int t = threadIdx.x + 32; t < 256; t += 32) {
        s += shS[t];
        s2 += shS2[t];
      }
      atomicAdd(&stats[2 * threadIdx.x], s.x);
      atomicAdd(&stats[2 * threadIdx.x + 1], s.y);
      atomicAdd(&stats[64 + 2 * threadIdx.x], s2.x);
      atomicAdd(&stats[64 + 2 * threadIdx.x + 1], s2.y);
    }
    __syncthreads();
    shS[threadIdx.x] = lsG;
    shS2[threadIdx.x] = ls2G;
    __syncthreads();
    if (threadIdx.x < 32) {
      f32x2 s = shS[threadIdx.x], s2 = shS2[threadIdx.x];
      for (int t = threadIdx.x + 32; t < 256; t += 32) {
        s += shS[t];
        s2 += shS2[t];
      }
      atomicAdd(&stats[128 + 2 * threadIdx.x], s.x);
      atomicAdd(&stats[128 + 2 * threadIdx.x + 1], s.y);
      atomicAdd(&stats[192 + 2 * threadIdx.x], s2.x);
      atomicAdd(&stats[192 + 2 * threadIdx.x + 1], s2.y);
    }
  }
}

// ---------------- merged readout ----------------
__global__ void __launch_bounds__(256) k_readout(const float* __restrict__ x,
                                                 const float* __restrict__ Wb,
                                                 const float* __restrict__ bb_,
                                                 const float* __restrict__ Wg,
                                                 const float* __restrict__ bg_,
                                                 float* __restrict__ out) {
  __shared__ float WsB[2048];
  __shared__ float WsG[2048];
  __shared__ float bsB[32];
  __shared__ float bsG[32];
  for (int i = threadIdx.x; i < 2048; i += 256) {
    WsB[i] = Wb[i];
    WsG[i] = Wg[i];
  }
  if (threadIdx.x < 32) {
    bsB[threadIdx.x] = bb_[threadIdx.x];
    bsG[threadIdx.x] = bg_[threadIdx.x];
  }
  __syncthreads();
  int lane = threadIdx.x & 63;
  int ch = lane & 31;
  int w = (blockIdx.x * blockDim.x + threadIdx.x) >> 6;
  int nw = (gridDim.x * blockDim.x) >> 6;
  for (int g = w; g < NALL; g += nw) {
    bool isBus = g < NBUS;
    const float* Ws = isBus ? WsB : WsG;
    float v = x[(size_t)g * 64 + lane];
    float acc = isBus ? bsB[ch] : bsG[ch];
#pragma unroll
    for (int i = 0; i < 64; i++) {
      float xi = __shfl(v, i, 64);
      acc = fmaf(xi, Ws[i * 32 + ch], acc);
    }
    if (lane < 32) out[(size_t)g * 32 + ch] = acc;  // bus/gen sections are contiguous
  }
}

extern "C" void kernel_launch(void* const* d_in, const int* in_sizes, int n_in,
                              void* d_out, int out_size, void* d_ws, size_t ws_size,
                              hipStream_t stream) {
  const float* x_bus = (const float*)d_in[0];
  const float* x_gen = (const float*)d_in[1];
  const float* riWb = (const float*)d_in[2];
  const float* ribb = (const float*)d_in[3];
  const float* riWg = (const float*)d_in[4];
  const float* ribg = (const float*)d_in[5];
  const float* bng_b = (const float*)d_in[6];
  const float* bnb_b = (const float*)d_in[7];
  const float* bng_g = (const float*)d_in[8];
  const float* bnb_g = (const float*)d_in[9];
  const float* tWb = (const float*)d_in[10];
  const float* tbb = (const float*)d_in[11];
  const float* tWg = (const float*)d_in[12];
  const float* tbg = (const float*)d_in[13];
  const float* roWb = (const float*)d_in[14];
  const float* robb = (const float*)d_in[15];
  const float* roWg = (const float*)d_in[16];
  const float* robg = (const float*)d_in[17];
  const int* ebb = (const int*)d_in[18];
  const int* gb_src = (const int*)d_in[19];
  const int* gb_dst = (const int*)d_in[20];
  const int* bg_src = (const int*)d_in[21];
  const int* bg_dst = (const int*)d_in[22];
  const int* bb_src = ebb;
  const int* bb_dst = ebb + NEBB;

  // ---- workspace layout (256B aligned segments) ----
  char* p = (char*)d_ws;
  auto take = [&](size_t bytes) -> void* {
    void* r = (void*)p;
    p += (bytes + 255) & ~(size_t)255;
    return r;
  };
  float* x = (float*)take((size_t)NALL * 64 * 4);  // bus rows [0,NBUS), gen rows after
  u16* buf0 = (u16*)take((size_t)NALL * 64 * 2);   // bf16 shift-state buffers
  u16* buf1 = (u16*)take((size_t)NALL * 64 * 2);
  int* bus_off = (int*)take((size_t)(NBUS + 1) * 4);
  int* bus_cur = (int*)take((size_t)NBUS * 4);
  int* bus_srt = (int*)take((size_t)NEBUS * 4);
  int* bg_off = (int*)take((size_t)(NGEN + 1) * 4);
  int* bg_cur = (int*)take((size_t)NGEN * 4);
  int* bg_srt = (int*)take((size_t)NEBG * 4);
  int* bsums = (int*)take(256 * 4);
  float* stats0 = (float*)take(256 * 4);  // [bus s, bus s2, gen s, gen s2]
  float* stats1 = (float*)take(256 * 4);
  if ((size_t)(p - (char*)d_ws) > ws_size) return;  // ws too small -> visible validation failure

  // ---- CSR build (merged bus CSR: bb edges + gb edges with src+NBUS) ----
  hipMemsetAsync(bus_cur, 0, (size_t)NBUS * 4, stream);
  hipMemsetAsync(bg_cur, 0, (size_t)NGEN * 4, stream);
  hipMemsetAsync(stats0, 0, 512 * 4, stream);  // stats0 + stats1 (contiguous)

  k_hist<<<2048, 256, 0, stream>>>(bb_dst, bus_cur, NEBB);
  k_hist<<<256, 256, 0, stream>>>(gb_dst, bus_cur, NEGB);
  k_hist<<<256, 256, 0, stream>>>(bg_dst, bg_cur, NEBG);

  k_scan1<<<128, 256, 0, stream>>>(bus_cur, bus_off, bsums, NBUS);
  k_scan2<<<1, 256, 0, stream>>>(bsums, 128);
  k_scan3<<<512, 256, 0, stream>>>(bus_off, bus_cur, bsums, NBUS, NEBUS);

  k_scan1<<<32, 256, 0, stream>>>(bg_cur, bg_off, bsums, NGEN);
  k_scan2<<<1, 256, 0, stream>>>(bsums, 32);
  k_scan3<<<128, 256, 0, stream>>>(bg_off, bg_cur, bsums, NGEN, NEBG);

  k_fill<<<2048, 256, 0, stream>>>(bb_src, bb_dst, bus_cur, bus_srt, NEBB, 0);
  k_fill<<<256, 256, 0, stream>>>(gb_src, gb_dst, bus_cur, bus_srt, NEGB, NBUS);
  k_fill<<<256, 256, 0, stream>>>(bg_src, bg_dst, bg_cur, bg_srt, NEBG, 0);

  // ---- readin (+ layer-0 BN stats) ----
  k_readin<<<5120, 256, 0, stream>>>(x_bus, x_gen, riWb, ribb, riWg, ribg, x, stats0);

  // ---- residual blocks ----
  u16* cur = buf0;
  u16* nxt = buf1;
  for (int l = 0; l < 2; l++) {
    float* statsL = (l == 0) ? stats0 : stats1;
    k_norm_tap0<<<5120, 256, 0, stream>>>(x, cur, statsL,
                                          bng_b + l * 64, bnb_b + l * 64,
                                          bng_g + l * 64, bnb_g + l * 64,
                                          tWb + (size_t)(l * 5) * 4096,
                                          tbb + (size_t)(l * 5) * 64,
                                          tWg + (size_t)(l * 5) * 4096,
                                          tbg + (size_t)(l * 5) * 64);
    for (int k = 1; k < 5; k++) {
      float* so = (l == 0 && k == 4) ? stats1 : (float*)nullptr;
      k_pull_tap<<<4096, 256, 0, stream>>>(bus_off, bus_srt, bg_off, bg_srt, cur, x, nxt,
                                           tWb + (size_t)(l * 5 + k) * 4096,
                                           tbb + (size_t)(l * 5 + k) * 64,
                                           tWg + (size_t)(l * 5 + k) * 4096,
                                           tbg + (size_t)(l * 5 + k) * 64, so);
      u16* t = cur; cur = nxt; nxt = t;
    }
  }

  // ---- readout ----
  k_readout<<<5120, 256, 0, stream>>>(x, roWb, robb, roWg, robg, (float*)d_out);
}